// Round 1
// baseline (116.252 us; speedup 1.0000x reference)
//
#include <hip/hip_runtime.h>

#define NN    2048      // number of notes
#define SEGL  32768     // max note length
#define NH    8         // harmonics
#define DURS  4194304   // output duration samples
#define TILE  2048      // output samples per block
#define BLK   256
#define SPT   (TILE / BLK)   // samples per thread

// Accurate sinf for 0 <= x < ~2^18, matching np.sin on the fp32 argument to ~1e-7.
// 2-term fp32 Cody-Waite reduction mod pi + degree-11 odd Taylor.
__device__ __forceinline__ float sin_acc(float x) {
    const float INV_PI = 0.31830988618379067f;
    float k = rintf(x * INV_PI);
    // pi = pi_hi + pi_mid; pi_hi = 0x1.921FB4p+1 (exactly representable)
    float r = fmaf(k, -0x1.921FB4p+1f, x);      // single rounding via fma
    r = fmaf(k, -6.2783296e-7f, r);             // pi_mid = fp32(pi - pi_hi)
    int ki = (int)k;
    float y = r * r;
    // sin(r) = r + r^3 * P(r^2), Taylor to x^11 (|err| < 6e-8 on [-pi/2,pi/2])
    float p = fmaf(y, -2.5052108e-8f, 2.7557319e-6f);
    p = fmaf(y, p, -1.9841270e-4f);
    p = fmaf(y, p, 8.3333333e-3f);
    p = fmaf(y, p, -1.6666667e-1f);
    float s = fmaf(r * y, p, r);
    return (ki & 1) ? -s : s;
}

// tanh(x) = 1 - 2/(e^{2x}+1); handles saturation via exp->inf/0 naturally.
__device__ __forceinline__ float tanh_fast(float x) {
    float e = __expf(2.0f * x);
    float rc = __builtin_amdgcn_rcpf(e + 1.0f);
    return fmaf(-2.0f, rc, 1.0f);
}

__global__ __launch_bounds__(BLK) void synth_gather(
    const float* __restrict__ freq,
    const float* __restrict__ amps,
    const float* __restrict__ gainp,
    const int*  __restrict__ starts,
    const int*  __restrict__ lens,
    float* __restrict__ out)
{
    __shared__ float s_freq[NN];
    __shared__ int   s_start[NN];
    __shared__ int   s_len[NN];

    const int tile_lo = (int)blockIdx.x * TILE;
    const int tile_hi = tile_lo + TILE;

    // Candidate notes = contiguous range [j0, j1) in the sorted start array.
    // Uniform binary searches (all threads identical -> no divergence).
    int lo = 0, hi = NN;
    const int v0 = tile_lo - SEGL;
    while (lo < hi) { int m = (lo + hi) >> 1; if (starts[m] > v0) hi = m; else lo = m + 1; }
    const int j0 = lo;
    lo = 0; hi = NN;
    while (lo < hi) { int m = (lo + hi) >> 1; if (starts[m] >= tile_hi) hi = m; else lo = m + 1; }
    const int j1 = lo;
    const int cnt = j1 - j0;

    // Stage candidate note metadata to LDS (broadcast reads later are conflict-free).
    for (int j = j0 + (int)threadIdx.x; j < j1; j += BLK) {
        int c = j - j0;
        s_freq[c] = freq[j];
        int st = starts[j];
        int ln = lens[j];
        int rem = DURS - st;            // reference: out_len = min(start+len, dur) - start
        if (rem < 0) rem = 0;           // also covers the (start < dur) validity check
        if (ln > rem) ln = rem;
        if (ln < 0) ln = 0;
        s_start[c] = st;
        s_len[c] = ln;
    }
    __syncthreads();

    float a[NH];
#pragma unroll
    for (int h = 0; h < NH; ++h) a[h] = amps[h];
    const float gain = gainp[0];

    float acc[SPT];
#pragma unroll
    for (int k = 0; k < SPT; ++k) acc[k] = 0.0f;

    const int base = tile_lo + (int)threadIdx.x;

    for (int c = 0; c < cnt; ++c) {
        const float fr = s_freq[c];
        const int st = s_start[c];
        const int ln = s_len[c];
#pragma unroll
        for (int k = 0; k < SPT; ++k) {
            const int t = base + k * BLK - st;
            if ((unsigned)t < (unsigned)ln) {
                // Match reference fp32 rounding: phase = fp32(freq*t); arg = fp32((h+1)*phase)
                const float phase = fr * (float)t;
                float seg = 0.0f;
#pragma unroll
                for (int h = 0; h < NH; ++h) {
                    const float arg = (float)(h + 1) * phase;
                    seg = fmaf(a[h], sin_acc(arg), seg);
                }
                acc[k] += tanh_fast(gain * seg);
            }
        }
    }

#pragma unroll
    for (int k = 0; k < SPT; ++k) {
        out[base + k * BLK] = acc[k];
    }
}

extern "C" void kernel_launch(void* const* d_in, const int* in_sizes, int n_in,
                              void* d_out, int out_size, void* d_ws, size_t ws_size,
                              hipStream_t stream) {
    const float* freq   = (const float*)d_in[0];
    const float* amps   = (const float*)d_in[1];
    const float* gain   = (const float*)d_in[2];
    const int*   starts = (const int*)d_in[3];
    const int*   lens   = (const int*)d_in[4];
    float* out = (float*)d_out;

    const int grid = DURS / TILE;   // 2048 blocks
    synth_gather<<<grid, BLK, 0, stream>>>(freq, amps, gain, starts, lens, out);
}

// Round 2
// 52.973 us; speedup vs baseline: 2.1946x; 2.1946x over previous
//
#include <hip/hip_runtime.h>

#define NN    2048      // number of notes
#define SEGL  32768     // max note length
#define NH    8         // harmonics
#define DURS  4194304   // output duration samples
#define TILE  2048      // output samples per block
#define BLK   256
#define SPT   (TILE / BLK)   // samples per thread
#define MAXC  256            // staged candidates per chunk (expected ~17)

// ---- accurate shared sincos for 0 <= x < ~2^16 ----------------------------
// One Cody-Waite reduction mod pi; sin/cos Taylor on [-pi/2, pi/2];
// sign (-1)^k applied to both via bit-xor.
// pi_hi = fp32(pi) = 0x1.921FB6p+1 (fma product k*pi_hi is exact inside fma)
// pi_mid = fp32(pi - pi_hi) = -0x1.777A5Cp-24  (~ -8.742278e-8)
// residual |pi - hi - mid| ~ 1e-15; k <= ~10430 -> negligible.
__device__ __forceinline__ void sincos_acc(float x, float& s_out, float& c_out) {
    const float INV_PI = 0.31830988618379067f;
    float kq = rintf(x * INV_PI);
    float r = fmaf(kq, -0x1.921FB6p+1f, x);     // exact product, single round
    r = fmaf(kq, 8.7422777e-8f, r);             // -(-8.742e-8) correction
    int ki = (int)kq;
    unsigned sgn = ((unsigned)ki) << 31;        // bit31 = parity of k
    float y = r * r;
    // sin(r) = r + r*y*P(y), |err| < 6e-8
    float sp = fmaf(y, -2.5052108e-8f, 2.7557319e-6f);
    sp = fmaf(y, sp, -1.9841270e-4f);
    sp = fmaf(y, sp, 8.3333333e-3f);
    sp = fmaf(y, sp, -1.6666667e-1f);
    float s = fmaf(r * y, sp, r);
    // cos(r) = 1 + y*Q(y), |err| < 5e-7
    float cp = fmaf(y, -2.7557319e-7f, 2.4801587e-5f);
    cp = fmaf(y, cp, -1.3888889e-3f);
    cp = fmaf(y, cp, 4.1666668e-2f);
    cp = fmaf(y, cp, -0.5f);
    float c = fmaf(y, cp, 1.0f);
    s_out = __uint_as_float(__float_as_uint(s) ^ sgn);
    c_out = __uint_as_float(__float_as_uint(c) ^ sgn);
}

__global__ __launch_bounds__(BLK) void synth_gather(
    const float* __restrict__ freq,
    const float* __restrict__ amps,
    const float* __restrict__ gainp,
    const int*  __restrict__ starts,
    const int*  __restrict__ lens,
    float* __restrict__ out)
{
    __shared__ float s_freq[MAXC];
    __shared__ int   s_start[MAXC];
    __shared__ int   s_len[MAXC];

    const int tile_lo = (int)blockIdx.x * TILE;
    const int tile_hi = tile_lo + TILE;

    // Candidate notes = contiguous range [j0, j1) in the sorted start array.
    int lo = 0, hi = NN;
    const int v0 = tile_lo - SEGL;
    while (lo < hi) { int m = (lo + hi) >> 1; if (starts[m] > v0) hi = m; else lo = m + 1; }
    const int j0 = lo;
    lo = 0; hi = NN;
    while (lo < hi) { int m = (lo + hi) >> 1; if (starts[m] >= tile_hi) hi = m; else lo = m + 1; }
    const int j1 = lo;

    float a[NH];
#pragma unroll
    for (int h = 0; h < NH; ++h) a[h] = amps[h];
    // tanh(g*x) = 1 - 2/(exp2(x * (2*g*log2e)) + 1)
    const float kg = gainp[0] * 2.8853900817779268f;   // 2*log2(e)

    float acc[SPT];
#pragma unroll
    for (int k = 0; k < SPT; ++k) acc[k] = 0.0f;

    const int base = tile_lo + (int)threadIdx.x;

    for (int jb = j0; jb < j1; jb += MAXC) {
        const int cchunk = min(j1 - jb, MAXC);
        __syncthreads();
        for (int c = (int)threadIdx.x; c < cchunk; c += BLK) {
            int j = jb + c;
            s_freq[c] = freq[j];
            int st = starts[j];
            int ln = lens[j];
            int rem = DURS - st;          // out_len = min(start+len, dur) - start
            if (rem < 0) rem = 0;
            if (ln > rem) ln = rem;
            if (ln < 0) ln = 0;
            s_start[c] = st;
            s_len[c] = ln;
        }
        __syncthreads();

        for (int c = 0; c < cchunk; ++c) {
            const float fr = s_freq[c];
            const int st = s_start[c];
            const int ln = s_len[c];
            const int tof = base - st;
#pragma unroll
            for (int k = 0; k < SPT; ++k) {
                const int t = tof + k * BLK;
                if ((unsigned)t < (unsigned)ln) {
                    // phase = fp32(freq*t) matches reference arg for h=1 exactly
                    const float ph = fr * (float)t;
                    float s1, c1;
                    sincos_acc(ph, s1, c1);
                    const float tc = c1 + c1;
                    // Chebyshev: s_{h+1} = 2c*s_h - s_{h-1}
                    const float s2 = tc * s1;
                    const float s3 = fmaf(tc, s2, -s1);
                    const float s4 = fmaf(tc, s3, -s2);
                    const float s5 = fmaf(tc, s4, -s3);
                    const float s6 = fmaf(tc, s5, -s4);
                    const float s7 = fmaf(tc, s6, -s5);
                    const float s8 = fmaf(tc, s7, -s6);
                    float seg = a[0] * s1;
                    seg = fmaf(a[1], s2, seg);
                    seg = fmaf(a[2], s3, seg);
                    seg = fmaf(a[3], s4, seg);
                    seg = fmaf(a[4], s5, seg);
                    seg = fmaf(a[5], s6, seg);
                    seg = fmaf(a[6], s7, seg);
                    seg = fmaf(a[7], s8, seg);
                    // tanh via exp2 (one mul + v_exp + v_rcp)
                    const float e = __builtin_amdgcn_exp2f(seg * kg);
                    const float rc = __builtin_amdgcn_rcpf(e + 1.0f);
                    acc[k] += fmaf(-2.0f, rc, 1.0f);
                }
            }
        }
    }

#pragma unroll
    for (int k = 0; k < SPT; ++k) {
        out[base + k * BLK] = acc[k];
    }
}

extern "C" void kernel_launch(void* const* d_in, const int* in_sizes, int n_in,
                              void* d_out, int out_size, void* d_ws, size_t ws_size,
                              hipStream_t stream) {
    const float* freq   = (const float*)d_in[0];
    const float* amps   = (const float*)d_in[1];
    const float* gain   = (const float*)d_in[2];
    const int*   starts = (const int*)d_in[3];
    const int*   lens   = (const int*)d_in[4];
    float* out = (float*)d_out;

    const int grid = DURS / TILE;   // 2048 blocks
    synth_gather<<<grid, BLK, 0, stream>>>(freq, amps, gain, starts, lens, out);
}

// Round 3
// 44.378 us; speedup vs baseline: 2.6196x; 1.1937x over previous
//
#include <hip/hip_runtime.h>

#define NN    2048      // number of notes
#define SEGL  32768     // max note length
#define NH    8         // harmonics
#define DURS  4194304   // output duration samples
#define TILE  1024      // output samples per block (was 2048; finer for balance)
#define BLK   256
#define SPT   (TILE / BLK)   // samples per thread = 4
#define MAXC  64             // staged candidates per chunk (expected ~17, tail ~40)

// ---- accurate shared sincos for |x| < ~2^18 -------------------------------
// One Cody-Waite reduction mod pi; sin/cos Taylor on [-pi/2, pi/2];
// sign (-1)^k applied to both via bit-xor (Chebyshev recurrence then yields
// correctly-signed sin(h*x) automatically).
__device__ __forceinline__ void sincos_acc(float x, float& s_out, float& c_out) {
    const float INV_PI = 0.31830988618379067f;
    float kq = rintf(x * INV_PI);
    float r = fmaf(kq, -0x1.921FB6p+1f, x);     // pi_hi = fp32(pi), exact in fma
    r = fmaf(kq, 8.7422777e-8f, r);             // pi_mid = -(pi - pi_hi)
    int ki = (int)kq;
    unsigned sgn = ((unsigned)ki) << 31;        // bit31 = parity of k
    float y = r * r;
    float sp = fmaf(y, -2.5052108e-8f, 2.7557319e-6f);
    sp = fmaf(y, sp, -1.9841270e-4f);
    sp = fmaf(y, sp, 8.3333333e-3f);
    sp = fmaf(y, sp, -1.6666667e-1f);
    float s = fmaf(r * y, sp, r);
    float cp = fmaf(y, -2.7557319e-7f, 2.4801587e-5f);
    cp = fmaf(y, cp, -1.3888889e-3f);
    cp = fmaf(y, cp, 4.1666668e-2f);
    cp = fmaf(y, cp, -0.5f);
    float c = fmaf(y, cp, 1.0f);
    s_out = __uint_as_float(__float_as_uint(s) ^ sgn);
    c_out = __uint_as_float(__float_as_uint(c) ^ sgn);
}

__global__ __launch_bounds__(BLK) void synth_gather(
    const float* __restrict__ freq,
    const float* __restrict__ amps,
    const float* __restrict__ gainp,
    const int*  __restrict__ starts,
    const int*  __restrict__ lens,
    float* __restrict__ out)
{
    __shared__ float s_freq[MAXC];
    __shared__ int   s_start[MAXC];
    __shared__ int   s_len[MAXC];

    const int tile_lo = (int)blockIdx.x * TILE;
    const int tile_hi = tile_lo + TILE;

    // Candidate notes = contiguous range [j0, j1) in the sorted start array.
    int lo = 0, hi = NN;
    const int v0 = tile_lo - SEGL;
    while (lo < hi) { int m = (lo + hi) >> 1; if (starts[m] > v0) hi = m; else lo = m + 1; }
    const int j0 = lo;
    lo = 0; hi = NN;
    while (lo < hi) { int m = (lo + hi) >> 1; if (starts[m] >= tile_hi) hi = m; else lo = m + 1; }
    const int j1 = lo;

    float a[NH];
#pragma unroll
    for (int h = 0; h < NH; ++h) a[h] = amps[h];
    // tanh(g*x) = 1 - 2/(exp2(x * (2*g*log2e)) + 1)
    const float kg = gainp[0] * 2.8853900817779268f;   // 2*log2(e)

    float acc[SPT];
#pragma unroll
    for (int k = 0; k < SPT; ++k) acc[k] = 0.0f;

    const int base = tile_lo + (int)threadIdx.x;

    for (int jb = j0; jb < j1; jb += MAXC) {
        const int cchunk = min(j1 - jb, MAXC);
        __syncthreads();
        for (int c = (int)threadIdx.x; c < cchunk; c += BLK) {
            int j = jb + c;
            s_freq[c] = freq[j];
            int st = starts[j];
            int ln = lens[j];
            int rem = DURS - st;          // out_len = min(start+len, dur) - start
            if (rem < 0) rem = 0;
            if (ln > rem) ln = rem;
            if (ln < 0) ln = 0;
            s_start[c] = st;
            s_len[c] = ln;
        }
        __syncthreads();

        for (int c = 0; c < cchunk; ++c) {
            const float fr = s_freq[c];
            const int st = s_start[c];
            const int ln = s_len[c];
            const int tof = base - st;
#pragma unroll
            for (int k = 0; k < SPT; ++k) {
                const int t = tof + k * BLK;
                if ((unsigned)t < (unsigned)ln) {
                    // phase = fp32(freq*t) matches reference arg for h=1 exactly
                    const float ph = fr * (float)t;
                    float s1, c1;
                    sincos_acc(ph, s1, c1);
                    const float tc = c1 + c1;
                    const float s2 = tc * s1;
                    const float s3 = fmaf(tc, s2, -s1);
                    const float s4 = fmaf(tc, s3, -s2);
                    const float s5 = fmaf(tc, s4, -s3);
                    const float s6 = fmaf(tc, s5, -s4);
                    const float s7 = fmaf(tc, s6, -s5);
                    const float s8 = fmaf(tc, s7, -s6);
                    float seg = a[0] * s1;
                    seg = fmaf(a[1], s2, seg);
                    seg = fmaf(a[2], s3, seg);
                    seg = fmaf(a[3], s4, seg);
                    seg = fmaf(a[4], s5, seg);
                    seg = fmaf(a[5], s6, seg);
                    seg = fmaf(a[6], s7, seg);
                    seg = fmaf(a[7], s8, seg);
                    const float e = __builtin_amdgcn_exp2f(seg * kg);
                    const float rc = __builtin_amdgcn_rcpf(e + 1.0f);
                    acc[k] += fmaf(-2.0f, rc, 1.0f);
                }
            }
        }
    }

#pragma unroll
    for (int k = 0; k < SPT; ++k) {
        out[base + k * BLK] = acc[k];
    }
}

extern "C" void kernel_launch(void* const* d_in, const int* in_sizes, int n_in,
                              void* d_out, int out_size, void* d_ws, size_t ws_size,
                              hipStream_t stream) {
    const float* freq   = (const float*)d_in[0];
    const float* amps   = (const float*)d_in[1];
    const float* gain   = (const float*)d_in[2];
    const int*   starts = (const int*)d_in[3];
    const int*   lens   = (const int*)d_in[4];
    float* out = (float*)d_out;

    const int grid = DURS / TILE;   // 4096 blocks -> 16 per CU, 8 co-resident
    synth_gather<<<grid, BLK, 0, stream>>>(freq, amps, gain, starts, lens, out);
}